// Round 14
// baseline (256.576 us; speedup 1.0000x reference)
//
#include <hip/hip_runtime.h>
#include <math.h>

// out = gelu( BN(segment_sum(H[src]*w, dst)) @ W + b ), exact gelu.
// N=100000, E=3200000, D=HIDDEN=128, all f32.
//
// Round-14: cache-policy hints (single lever vs round 13).
//   nt(load):  pull's payload stage-read, hist_prep's streaming reads
//   nt(store): pull's hb_out, mfma's out, hist_prep's Hb  (all full-line)
//   NOT nt:    scatter's payload stores (need L2 write-combining of 8B tails)
// Pipeline unchanged (6 launches):
//   K1 hist_prep / K2 scan1 / K3 scan23(+ctr=0) / K4 scatter_blk /
//   K5 reorder_pull (persistent, LDS sort, 8-deep gather) / K6 mfma_gemm_gelu
// Fallbacks: tier B = f32 CSR path + VALU GEMM; tier C = atomic scatter.

#define DF 128
#define SCAN_ELEMS 2048
#define BKSH 6
#define BKNODES (1 << BKSH)
#define NB 256
#define CAP 4096       // tier-B reorder2 staging
#define CAP2 3072      // reorder_pull LDS entries (mean 2048)
#define PBLOCKS 512

typedef short short8 __attribute__((ext_vector_type(8)));
typedef float f32x4 __attribute__((ext_vector_type(4)));
typedef float f32v4 __attribute__((ext_vector_type(4)));

__device__ __forceinline__ unsigned short f32_to_bf16_rne(float f) {
  unsigned u = __float_as_uint(f);
  return (unsigned short)((u + 0x7FFFu + ((u >> 16) & 1u)) >> 16);
}

__device__ __forceinline__ uint2 nt_load_u2(const uint2* p) {
  unsigned long long v =
      __builtin_nontemporal_load((const unsigned long long*)p);
  uint2 r;
  r.x = (unsigned)v;
  r.y = (unsigned)(v >> 32);
  return r;
}

// ---------------- Tier C fallback ----------------
__global__ __launch_bounds__(256) void scatter_kernel(
    const float* __restrict__ H, const int* __restrict__ esrc,
    const int* __restrict__ edst, const float* __restrict__ ew,
    float* __restrict__ h, int E) {
  int tid = blockIdx.x * blockDim.x + threadIdx.x;
  int e = tid >> 5;
  int lane = tid & 31;
  if (e >= E) return;
  int s = esrc[e];
  int d = edst[e];
  float w = ew[e];
  const float4* Hs = reinterpret_cast<const float4*>(H + (size_t)s * DF);
  float4 v = Hs[lane];
  float* hd = h + (size_t)d * DF + lane * 4;
  atomicAdd(hd + 0, v.x * w);
  atomicAdd(hd + 1, v.y * w);
  atomicAdd(hd + 2, v.z * w);
  atomicAdd(hd + 3, v.w * w);
}

// ---------------- fused hist + prep (block-role split) ----------------
__global__ __launch_bounds__(512) void hist_prep_kernel(
    const int* __restrict__ edst, int* __restrict__ gbase,
    int E, int nbk, int chunk,
    const float* __restrict__ H, ushort4* __restrict__ Hb, int n4,
    const float* __restrict__ W, const float* __restrict__ gamma,
    const float* __restrict__ beta, const float* __restrict__ mean,
    const float* __restrict__ var, const float* __restrict__ b,
    unsigned short* __restrict__ W2frag, float* __restrict__ bias2,
    int nb_hist, int h_blocks) {
  extern __shared__ int hcnt[];
  int bid = blockIdx.x;
  int t = threadIdx.x;

  if (bid < nb_hist) {
    for (int i = t; i < nbk; i += 512) hcnt[i] = 0;
    __syncthreads();
    int e0 = bid * chunk;
    int e1 = min(E, e0 + chunk);
    for (int e = e0 + t; e < e1; e += 512) {
      int d = __builtin_nontemporal_load(edst + e);
      atomicAdd(&hcnt[d >> BKSH], 1);
    }
    __syncthreads();
    for (int k = t; k < nbk; k += 512)
      gbase[(size_t)k * NB + bid] = hcnt[k];
  } else if (bid < nb_hist + h_blocks) {
    int idx = (bid - nb_hist) * 512 + t;
    if (idx < n4) {
      const f32v4* H4 = (const f32v4*)H;
      f32v4 v = __builtin_nontemporal_load(H4 + idx);
      ushort4 o;
      o.x = f32_to_bf16_rne(v.x);
      o.y = f32_to_bf16_rne(v.y);
      o.z = f32_to_bf16_rne(v.z);
      o.w = f32_to_bf16_rne(v.w);
      unsigned long long pk = (unsigned long long)o.x |
                              ((unsigned long long)o.y << 16) |
                              ((unsigned long long)o.z << 32) |
                              ((unsigned long long)o.w << 48);
      __builtin_nontemporal_store(pk, (unsigned long long*)(Hb + idx));
    }
  } else if (bid < nb_hist + h_blocks + 32) {
    int idx = (bid - nb_hist - h_blocks) * 512 + t;  // 0..16383
    if (idx < 16384) {
      int i = idx & 7;
      int l = (idx >> 3) & 63;
      int kt = (idx >> 9) & 3;
      int ct = idx >> 11;
      int k = kt * 32 + (l >> 4) * 8 + i;
      int c = ct * 16 + (l & 15);
      float s = gamma[k] * rsqrtf(var[k] + 1e-3f);
      W2frag[idx] = f32_to_bf16_rne(s * W[(size_t)k * DF + c]);
    }
  } else {
    if (t < DF) {
      int c = t;
      float acc = b[c];
      for (int k = 0; k < DF; ++k) {
        float s = gamma[k] * rsqrtf(var[k] + 1e-3f);
        float tt = beta[k] - mean[k] * s;
        acc += tt * W[(size_t)k * DF + c];
      }
      bias2[c] = acc;
    }
  }
}

// ---------------- scans (in-place over gbase) ----------------
__global__ __launch_bounds__(256) void scan1_kernel(
    int* __restrict__ data, int* __restrict__ bsum, int n) {
  __shared__ int s[256];
  int t = threadIdx.x;
  int base = blockIdx.x * SCAN_ELEMS + t * 8;
  int v[8];
  int tsum = 0;
#pragma unroll
  for (int k = 0; k < 8; ++k) {
    v[k] = (base + k < n) ? data[base + k] : 0;
    tsum += v[k];
  }
  s[t] = tsum;
  __syncthreads();
  for (int off = 1; off < 256; off <<= 1) {
    int tmp = (t >= off) ? s[t - off] : 0;
    __syncthreads();
    s[t] += tmp;
    __syncthreads();
  }
  int run = s[t] - tsum;
#pragma unroll
  for (int k = 0; k < 8; ++k) {
    if (base + k < n) data[base + k] = run;
    run += v[k];
  }
  if (t == 255) bsum[blockIdx.x] = s[255];
}

__global__ __launch_bounds__(256) void scan23_kernel(
    int* __restrict__ data, const int* __restrict__ bsum, int n, int nbA,
    int* __restrict__ ctr) {
  __shared__ int s[256];
  int t = threadIdx.x;
  int v = (t < nbA) ? bsum[t] : 0;
  s[t] = v;
  __syncthreads();
  for (int off = 1; off < 256; off <<= 1) {
    int tmp = (t >= off) ? s[t - off] : 0;
    __syncthreads();
    s[t] += tmp;
    __syncthreads();
  }
  int i = blockIdx.x * 256 + t;
  if (i < n) {
    int blk = i >> 11;  // SCAN_ELEMS = 2048
    int add = (blk == 0) ? 0 : s[blk - 1];
    data[i] += add;
  }
  if (blockIdx.x == 0 && t == 0) {
    data[n] = s[nbA - 1];
    ctr[0] = 0;  // work-stealing queue init
  }
}

// ---------------- scatter into bucket-sorted payload ----------------
// NOTE: payload stores stay NORMAL (L2 write-combining merges 8B tails).
__global__ __launch_bounds__(512) void scatter_blk_kernel(
    const int* __restrict__ esrc, const int* __restrict__ edst,
    const float* __restrict__ ew, const int* __restrict__ gbase,
    uint2* __restrict__ payload, int E, int nbk, int chunk) {
  extern __shared__ int cur[];
  int bblk = blockIdx.x;
  int t = threadIdx.x;
  for (int k = t; k < nbk; k += 512) cur[k] = gbase[(size_t)k * NB + bblk];
  __syncthreads();
  int e0 = bblk * chunk;
  int e1 = min(E, e0 + chunk);
  for (int e = e0 + t; e < e1; e += 512) {
    int d = edst[e];
    int k = d >> BKSH;
    int pos = atomicAdd(&cur[k], 1);
    uint2 v;
    v.x = (unsigned)esrc[e] | ((unsigned)(d & (BKNODES - 1)) << 17);
    v.y = __float_as_uint(ew[e]);
    payload[pos] = v;
  }
}

// ---------------- persistent fused reorder + pull ----------------
__global__ __launch_bounds__(1024, 8) void reorder_pull_kernel(
    const unsigned* __restrict__ Hb, const uint2* __restrict__ payload,
    const int* __restrict__ gbase, unsigned* __restrict__ hb_out,
    int* __restrict__ ctr, int N, int nbk) {
  __shared__ uint2 stage[CAP2];    // 24 KB
  __shared__ uint2 sorted[CAP2];   // 24 KB
  __shared__ int cnt[BKNODES];
  __shared__ int scn[BKNODES];
  __shared__ int cur[BKNODES];
  __shared__ int s_bk;
  int t = threadIdx.x;
  int wid = t >> 6;
  int lane = t & 63;

  for (;;) {
    if (t == 0) s_bk = atomicAdd(ctr, 1);
    __syncthreads();
    int bk = s_bk;
    if (bk >= nbk) return;
    int base = gbase[(size_t)bk * NB];
    int end  = gbase[(size_t)(bk + 1) * NB];
    int len = end - base;

    if (len <= CAP2) {
      if (t < BKNODES) cnt[t] = 0;
      __syncthreads();
      // single global read of the segment: stage + count.
      // nt: read-once stream; don't evict gathered Hb rows from L2.
      for (int j = t; j < len; j += 1024) {
        uint2 m = nt_load_u2(&payload[base + j]);
        stage[j] = m;
        atomicAdd(&cnt[m.x >> 17], 1);
      }
      __syncthreads();
      if (t < BKNODES) scn[t] = cnt[t];
      __syncthreads();
      for (int off = 1; off < BKNODES; off <<= 1) {
        int tmp = (t < BKNODES && t >= off) ? scn[t - off] : 0;
        __syncthreads();
        if (t < BKNODES) scn[t] += tmp;
        __syncthreads();
      }
      if (t < BKNODES) cur[t] = scn[t] - cnt[t];
      __syncthreads();
      // LDS -> LDS bucket sort
      for (int j = t; j < len; j += 1024) {
        uint2 m = stage[j];
        int pos = atomicAdd(&cur[m.x >> 17], 1);
        uint2 o;
        o.x = m.x & 0x1FFFFu;
        o.y = m.y;
        sorted[pos] = o;
      }
      __syncthreads();

      // gather: wave handles 4 nodes; 8 independent row gathers in flight
#pragma unroll
      for (int i = 0; i < 4; ++i) {
        int dl = wid * 4 + i;
        int node = (bk << BKSH) + dl;
        if (node >= N) break;
        int s1 = scn[dl];
        int s0 = s1 - cnt[dl];
        float ax = 0.0f, ay = 0.0f;
        int j = s0;
        for (; j + 8 <= s1; j += 8) {
          uint2 m[8];
#pragma unroll
          for (int k = 0; k < 8; ++k) m[k] = sorted[j + k];  // LDS broadcast
          float lo[8], hi[8];
#pragma unroll
          for (int k = 0; k < 8; ++k) {
            unsigned p = Hb[(size_t)m[k].x * 64 + lane];
            lo[k] = __uint_as_float(p << 16);
            hi[k] = __uint_as_float(p & 0xFFFF0000u);
          }
#pragma unroll
          for (int k = 0; k < 8; ++k) {
            float w = __uint_as_float(m[k].y);
            ax = fmaf(lo[k], w, ax);
            ay = fmaf(hi[k], w, ay);
          }
        }
        for (; j < s1; ++j) {
          uint2 m = sorted[j];
          float w = __uint_as_float(m.y);
          unsigned p = Hb[(size_t)m.x * 64 + lane];
          ax = fmaf(__uint_as_float(p << 16), w, ax);
          ay = fmaf(__uint_as_float(p & 0xFFFF0000u), w, ay);
        }
        unsigned pack = (unsigned)f32_to_bf16_rne(ax) |
                        ((unsigned)f32_to_bf16_rne(ay) << 16);
        // nt: full-line coalesced store, consumed later (other XCDs).
        __builtin_nontemporal_store(pack,
                                    hb_out + (size_t)node * 64 + lane);
      }
    } else {
      // Pathological bucket (>CAP2): filter-scan, correct but slow.
      for (int i = 0; i < 4; ++i) {
        int dl = wid * 4 + i;
        int node = (bk << BKSH) + dl;
        if (node >= N) break;
        float ax = 0.0f, ay = 0.0f;
        for (int j = base; j < end; ++j) {
          uint2 m = payload[j];
          if ((int)(m.x >> 17) == dl) {
            float w = __uint_as_float(m.y);
            unsigned p = Hb[(size_t)(m.x & 0x1FFFFu) * 64 + lane];
            ax = fmaf(__uint_as_float(p << 16), w, ax);
            ay = fmaf(__uint_as_float(p & 0xFFFF0000u), w, ay);
          }
        }
        unsigned pack = (unsigned)f32_to_bf16_rne(ax) |
                        ((unsigned)f32_to_bf16_rne(ay) << 16);
        hb_out[(size_t)node * 64 + lane] = pack;
      }
    }
    __syncthreads();  // LDS reuse + s_bk rewrite safety
  }
}

// ---------------- MFMA GEMM + GELU (BN pre-folded), 2 row-groups/block -----
__global__ __launch_bounds__(256) void mfma_gemm_gelu_kernel(
    const unsigned short* __restrict__ hb,      // [N][128] bf16
    const unsigned short* __restrict__ W2frag,  // fragment-ordered bf16
    const float* __restrict__ bias2,            // [128]
    float* __restrict__ out, int N, int ngrp) {
  __shared__ unsigned short sW[8 * 4 * 64 * 8];  // 32 KB

  int t = threadIdx.x;
  {
    const uint4* src = (const uint4*)W2frag;
    uint4* dst = (uint4*)sW;
    for (int i = t; i < 2048; i += 256) dst[i] = src[i];
  }
  __syncthreads();

  int wid = t >> 6;
  int l = t & 63;
  const short8* wf = (const short8*)sW;
  int orow = (l >> 4) * 4;  // C/D: row=(lane>>4)*4+reg, col=lane&15 (m89)
  int ocol = l & 15;

#pragma unroll
  for (int g = 0; g < 2; ++g) {
    int grp = blockIdx.x * 2 + g;
    if (grp >= ngrp) break;
    int row0 = grp * 64 + wid * 16;

    int arow = row0 + (l & 15);
    if (arow >= N) arow = N - 1;  // clamp (stores guarded)
    const short8* hrow = (const short8*)(hb + (size_t)arow * DF);
    int asub = l >> 4;
    short8 a[4];
#pragma unroll
    for (int kt = 0; kt < 4; ++kt) a[kt] = hrow[kt * 4 + asub];

#pragma unroll
    for (int ct = 0; ct < 8; ++ct) {
      f32x4 acc = {0.0f, 0.0f, 0.0f, 0.0f};
#pragma unroll
      for (int kt = 0; kt < 4; ++kt) {
        short8 bfr = wf[(ct * 4 + kt) * 64 + l];
        acc = __builtin_amdgcn_mfma_f32_16x16x32_bf16(a[kt], bfr, acc, 0, 0, 0);
      }
      int col = ct * 16 + ocol;
      float bb = bias2[col];
#pragma unroll
      for (int r = 0; r < 4; ++r) {
        int row = row0 + orow + r;
        if (row < N) {
          float x = acc[r] + bb;
          float gv = 0.5f * x * (1.0f + erff(x * 0.70710678118654752440f));
          // nt: output is never re-read; keep L2 for hb streams.
          __builtin_nontemporal_store(gv, out + (size_t)row * DF + col);
        }
      }
    }
  }
}

// ---------------- tier-B kernels (round-8 verified) ----------------
__global__ __launch_bounds__(256) void reorder2_kernel(
    const uint2* __restrict__ payload, const int* __restrict__ gbase,
    uint2* __restrict__ csr, int* __restrict__ rowptr,
    int N, int nbk, int E) {
  __shared__ uint2 stage[CAP];
  __shared__ int cnt[BKNODES];
  __shared__ int s64[BKNODES];
  __shared__ int cur[BKNODES];
  int bk = blockIdx.x;
  int t = threadIdx.x;
  int base = gbase[(size_t)bk * NB];
  int end  = gbase[(size_t)(bk + 1) * NB];
  int len = end - base;
  bool fit = (len <= CAP);

  if (t < BKNODES) cnt[t] = 0;
  __syncthreads();
  if (fit) {
    for (int j = t; j < len; j += 256) {
      uint2 m = payload[base + j];
      stage[j] = m;
      atomicAdd(&cnt[m.x >> 17], 1);
    }
  } else {
    for (int j = t; j < len; j += 256)
      atomicAdd(&cnt[payload[base + j].x >> 17], 1);
  }
  __syncthreads();
  if (t < BKNODES) s64[t] = cnt[t];
  __syncthreads();
  for (int off = 1; off < BKNODES; off <<= 1) {
    int tmp = 0;
    if (t < BKNODES && t >= off) tmp = s64[t - off];
    __syncthreads();
    if (t < BKNODES) s64[t] += tmp;
    __syncthreads();
  }
  if (t < BKNODES) {
    int ex = s64[t] - cnt[t];
    cur[t] = ex;
    int node = (bk << BKSH) + t;
    if (node < N) rowptr[node] = base + ex;
  }
  if (bk == nbk - 1 && t == 0) rowptr[N] = E;
  __syncthreads();
  if (fit) {
    for (int j = t; j < len; j += 256) {
      uint2 m = stage[j];
      int dl = (int)(m.x >> 17);
      int pos = atomicAdd(&cur[dl], 1);
      uint2 o;
      o.x = m.x & 0x1FFFFu;
      o.y = m.y;
      csr[(size_t)base + pos] = o;
    }
  } else {
    for (int j = t; j < len; j += 256) {
      uint2 m = payload[base + j];
      int dl = (int)(m.x >> 17);
      int pos = atomicAdd(&cur[dl], 1);
      uint2 o;
      o.x = m.x & 0x1FFFFu;
      o.y = m.y;
      csr[(size_t)base + pos] = o;
    }
  }
}

__global__ __launch_bounds__(256) void pull_csr_f32_kernel(
    const float2* __restrict__ H2, const int* __restrict__ rowptr,
    const uint2* __restrict__ csr_sw, float* __restrict__ h, int N) {
  int wave = threadIdx.x >> 6;
  int lane = threadIdx.x & 63;
  int node = blockIdx.x * 4 + wave;
  if (node >= N) return;
  int rs = rowptr[node];
  int re = rowptr[node + 1];
  float ax = 0.0f, ay = 0.0f;
  for (int j = rs; j < re; ++j) {
    uint2 m = csr_sw[j];
    float w = __uint_as_float(m.y);
    float2 u = H2[(size_t)m.x * 64 + lane];
    ax = fmaf(u.x, w, ax);
    ay = fmaf(u.y, w, ay);
  }
  float2 r;
  r.x = ax;
  r.y = ay;
  reinterpret_cast<float2*>(h)[(size_t)node * 64 + lane] = r;
}

__global__ __launch_bounds__(256) void fused_bn_gemm_gelu(
    float* __restrict__ hout, const float* __restrict__ gamma,
    const float* __restrict__ beta, const float* __restrict__ mean,
    const float* __restrict__ var, const float* __restrict__ W,
    const float* __restrict__ b, int N) {
  __shared__ float s_s[DF];
  __shared__ float s_t[DF];
  __shared__ float s_hb[16][DF];
  __shared__ float s_W[32][DF];

  int t = threadIdx.x;
  if (t < DF) {
    float sv = gamma[t] * rsqrtf(var[t] + 1e-3f);
    s_s[t] = sv;
    s_t[t] = beta[t] - mean[t] * sv;
  }
  __syncthreads();

  int n0 = blockIdx.x * 16;
  for (int i = t; i < 16 * DF; i += 256) {
    int r = i >> 7;
    int c = i & (DF - 1);
    int node = n0 + r;
    float hv = (node < N) ? hout[(size_t)node * DF + c] : 0.0f;
    s_hb[r][c] = hv * s_s[c] + s_t[c];
  }

  float acc[8];
#pragma unroll
  for (int i = 0; i < 8; i++) acc[i] = 0.0f;

  int col = t & (DF - 1);
  int half = t >> 7;

  for (int kc = 0; kc < DF; kc += 32) {
    __syncthreads();
    for (int i = t; i < 32 * DF; i += 256) {
      int r = i >> 7;
      int c = i & (DF - 1);
      s_W[r][c] = W[(size_t)(kc + r) * DF + c];
    }
    __syncthreads();
#pragma unroll
    for (int kk = 0; kk < 32; kk++) {
      float wv = s_W[kk][col];
#pragma unroll
      for (int i = 0; i < 8; i++) {
        acc[i] += s_hb[half + i * 2][kc + kk] * wv;
      }
    }
  }

  float bb = b[col];
#pragma unroll
  for (int i = 0; i < 8; i++) {
    int node = n0 + half + i * 2;
    if (node < N) {
      float x = acc[i] + bb;
      float g = 0.5f * x * (1.0f + erff(x * 0.70710678118654752440f));
      hout[(size_t)node * DF + col] = g;
    }
  }
}

extern "C" void kernel_launch(void* const* d_in, const int* in_sizes, int n_in,
                              void* d_out, int out_size, void* d_ws, size_t ws_size,
                              hipStream_t stream) {
  const float* H     = (const float*)d_in[0];
  const int*   esrc  = (const int*)d_in[1];
  const int*   edst  = (const int*)d_in[2];
  const float* ew    = (const float*)d_in[3];
  const float* gamma = (const float*)d_in[4];
  const float* beta  = (const float*)d_in[5];
  const float* mean  = (const float*)d_in[6];
  const float* var   = (const float*)d_in[7];
  const float* W     = (const float*)d_in[8];
  const float* b     = (const float*)d_in[9];

  int N = in_sizes[0] / DF;
  int E = in_sizes[1];
  float* h = (float*)d_out;

  int nbk = (N + BKNODES - 1) / BKNODES;          // 1563
  int NBKG = nbk * NB;                             // 400128
  int nbA = (NBKG + SCAN_ELEMS - 1) / SCAN_ELEMS;  // 196 <= 256
  int chunk = (E + NB - 1) / NB;                   // 12500

  size_t off = 0;
  auto alloc = [&](size_t bytes) {
    size_t o = off;
    off += (bytes + 255) & ~(size_t)255;
    return o;
  };
  size_t o_gbase  = alloc((size_t)(NBKG + 1) * 4);  // counts -> scanned bases
  size_t o_bsum   = alloc((size_t)(nbA + 1) * 4);
  size_t o_rowptr = alloc((size_t)(N + 1) * 4);     // tier B only
  size_t o_w2     = alloc((size_t)16384 * 2);
  size_t o_bias2  = alloc((size_t)DF * 4);
  size_t o_ctr    = alloc(256);
  size_t o_pl     = alloc((size_t)E * 8);
  size_t o_csr    = alloc((size_t)E * 8);   // tier A: reused as bf16 h out
  size_t need_bin = off;
  size_t o_hb     = alloc((size_t)N * DF * 2);
  size_t need_bf16 = off;

  char* ws = (char*)d_ws;

  if (ws_size >= need_bin) {
    int* gbase   = (int*)(ws + o_gbase);
    int* bsum    = (int*)(ws + o_bsum);
    int* rowptr  = (int*)(ws + o_rowptr);
    unsigned short* W2frag = (unsigned short*)(ws + o_w2);
    float* bias2 = (float*)(ws + o_bias2);
    int* ctr     = (int*)(ws + o_ctr);
    uint2* payload = (uint2*)(ws + o_pl);
    uint2* csr     = (uint2*)(ws + o_csr);
    bool tierA = (ws_size >= need_bf16 && (size_t)N * DF * 2 <= (size_t)E * 8);

    size_t lds_bytes = (size_t)nbk * 4;

    if (tierA) {
      ushort4* Hb = (ushort4*)(ws + o_hb);
      int n4 = N * DF / 4;                        // 3.2M
      int h_blocks = (n4 + 511) / 512;            // 6250
      int grid = NB + h_blocks + 32 + 1;
      hist_prep_kernel<<<grid, 512, lds_bytes, stream>>>(
          edst, gbase, E, nbk, chunk,
          H, Hb, n4,
          W, gamma, beta, mean, var, b, W2frag, bias2, NB, h_blocks);
      scan1_kernel<<<nbA, 256, 0, stream>>>(gbase, bsum, NBKG);
      scan23_kernel<<<(NBKG + 255) / 256, 256, 0, stream>>>(gbase, bsum, NBKG,
                                                            nbA, ctr);
      scatter_blk_kernel<<<NB, 512, lds_bytes, stream>>>(esrc, edst, ew, gbase,
                                                         payload, E, nbk, chunk);
      unsigned* hb_out = (unsigned*)(ws + o_csr);  // csr space reused
      int pgrid = min(PBLOCKS, nbk);
      reorder_pull_kernel<<<pgrid, 1024, 0, stream>>>(
          (const unsigned*)Hb, payload, gbase, hb_out, ctr, N, nbk);
      int ngrp = (N + 63) / 64;
      mfma_gemm_gelu_kernel<<<(ngrp + 1) / 2, 256, 0, stream>>>(
          (const unsigned short*)hb_out, W2frag, bias2, (float*)d_out, N, ngrp);
    } else {
      hist_prep_kernel<<<NB, 512, lds_bytes, stream>>>(
          edst, gbase, E, nbk, chunk,
          H, (ushort4*)(ws + o_pl) /*unused*/, 0,
          W, gamma, beta, mean, var, b, W2frag, bias2, NB, 0);
      scan1_kernel<<<nbA, 256, 0, stream>>>(gbase, bsum, NBKG);
      scan23_kernel<<<(NBKG + 255) / 256, 256, 0, stream>>>(gbase, bsum, NBKG,
                                                            nbA, ctr);
      scatter_blk_kernel<<<NB, 512, lds_bytes, stream>>>(esrc, edst, ew, gbase,
                                                         payload, E, nbk, chunk);
      reorder2_kernel<<<nbk, 256, 0, stream>>>(payload, gbase, csr, rowptr,
                                               N, nbk, E);
      pull_csr_f32_kernel<<<(N + 3) / 4, 256, 0, stream>>>(
          (const float2*)H, rowptr, csr, h, N);
      fused_bn_gemm_gelu<<<(N + 15) / 16, 256, 0, stream>>>(h, gamma, beta,
                                                            mean, var, W, b, N);
    }
  } else {
    hipMemsetAsync(d_out, 0, (size_t)out_size * sizeof(float), stream);
    long long threads = (long long)E * 32;
    long long grid = (threads + 255) / 256;
    scatter_kernel<<<(int)grid, 256, 0, stream>>>(H, esrc, edst, ew, h, E);
    fused_bn_gemm_gelu<<<(N + 15) / 16, 256, 0, stream>>>(h, gamma, beta,
                                                          mean, var, W, b, N);
  }
}

// Round 15
// 224.472 us; speedup vs baseline: 1.1430x; 1.1430x over previous
//
#include <hip/hip_runtime.h>
#include <math.h>

// out = gelu( BN(segment_sum(H[src]*w, dst)) @ W + b ), exact gelu.
// N=100000, E=3200000, D=HIDDEN=128, all f32.
//
// Round-15: REVERT to round-13 (best verified: 226 us). Round-14's
// nontemporal hints regressed (-30 us): nt stores bypass L2 write-allocate,
// hurting producer->consumer reuse (Hb, out). No other changes.
//   K1: hist_prep    blocks [0,NB): LDS bucket hist -> gbase[k][b];
//                    blocks [NB,..): H->bf16, W2frag, bias2 (concurrent)
//   K2: scan1        in-place exclusive scan (2048/block), bsum
//   K3: scan23       re-scan bsum in LDS, finalize gbase, ctr=0
//   K4: scatter_blk  LDS cursors, bucket-sorted payload (no global atomics)
//   K5: reorder_pull 512 persistent blocks, atomic bucket queue; stage seg in
//                    LDS (ONE global read), LDS sort, 16 waves x 4 nodes
//                    8-deep gather; PACKED BF16 h out
//   K6: mfma_gemm_gelu  16x16x32 bf16 MFMA, BN folded, 2 row-groups/block
// Fallbacks: tier B = f32 CSR path + VALU GEMM; tier C = atomic scatter.

#define DF 128
#define SCAN_ELEMS 2048
#define BKSH 6
#define BKNODES (1 << BKSH)
#define NB 256
#define CAP 4096       // tier-B reorder2 staging
#define CAP2 3072      // reorder_pull LDS entries (mean 2048)
#define PBLOCKS 512

typedef short short8 __attribute__((ext_vector_type(8)));
typedef float f32x4 __attribute__((ext_vector_type(4)));

__device__ __forceinline__ unsigned short f32_to_bf16_rne(float f) {
  unsigned u = __float_as_uint(f);
  return (unsigned short)((u + 0x7FFFu + ((u >> 16) & 1u)) >> 16);
}

// ---------------- Tier C fallback ----------------
__global__ __launch_bounds__(256) void scatter_kernel(
    const float* __restrict__ H, const int* __restrict__ esrc,
    const int* __restrict__ edst, const float* __restrict__ ew,
    float* __restrict__ h, int E) {
  int tid = blockIdx.x * blockDim.x + threadIdx.x;
  int e = tid >> 5;
  int lane = tid & 31;
  if (e >= E) return;
  int s = esrc[e];
  int d = edst[e];
  float w = ew[e];
  const float4* Hs = reinterpret_cast<const float4*>(H + (size_t)s * DF);
  float4 v = Hs[lane];
  float* hd = h + (size_t)d * DF + lane * 4;
  atomicAdd(hd + 0, v.x * w);
  atomicAdd(hd + 1, v.y * w);
  atomicAdd(hd + 2, v.z * w);
  atomicAdd(hd + 3, v.w * w);
}

// ---------------- fused hist + prep (block-role split) ----------------
// blocks [0, nb_hist): LDS bucket histogram of a chunk -> gbase[k][b]
// blocks [nb_hist, nb_hist+h_blocks): H -> bf16 (RNE)
// next 32 blocks: W2frag = diag(s)*W in MFMA B-fragment order
// last block: bias2[c] = b[c] + sum_k (beta[k]-mean[k]*s[k]) * W[k][c]
__global__ __launch_bounds__(512) void hist_prep_kernel(
    const int* __restrict__ edst, int* __restrict__ gbase,
    int E, int nbk, int chunk,
    const float4* __restrict__ H4, ushort4* __restrict__ Hb, int n4,
    const float* __restrict__ W, const float* __restrict__ gamma,
    const float* __restrict__ beta, const float* __restrict__ mean,
    const float* __restrict__ var, const float* __restrict__ b,
    unsigned short* __restrict__ W2frag, float* __restrict__ bias2,
    int nb_hist, int h_blocks) {
  extern __shared__ int hcnt[];
  int bid = blockIdx.x;
  int t = threadIdx.x;

  if (bid < nb_hist) {
    for (int i = t; i < nbk; i += 512) hcnt[i] = 0;
    __syncthreads();
    int e0 = bid * chunk;
    int e1 = min(E, e0 + chunk);
    for (int e = e0 + t; e < e1; e += 512)
      atomicAdd(&hcnt[edst[e] >> BKSH], 1);
    __syncthreads();
    for (int k = t; k < nbk; k += 512)
      gbase[(size_t)k * NB + bid] = hcnt[k];
  } else if (bid < nb_hist + h_blocks) {
    int idx = (bid - nb_hist) * 512 + t;
    if (idx < n4) {
      float4 v = H4[idx];
      ushort4 o;
      o.x = f32_to_bf16_rne(v.x);
      o.y = f32_to_bf16_rne(v.y);
      o.z = f32_to_bf16_rne(v.z);
      o.w = f32_to_bf16_rne(v.w);
      Hb[idx] = o;
    }
  } else if (bid < nb_hist + h_blocks + 32) {
    int idx = (bid - nb_hist - h_blocks) * 512 + t;  // 0..16383
    if (idx < 16384) {
      int i = idx & 7;
      int l = (idx >> 3) & 63;
      int kt = (idx >> 9) & 3;
      int ct = idx >> 11;
      int k = kt * 32 + (l >> 4) * 8 + i;
      int c = ct * 16 + (l & 15);
      float s = gamma[k] * rsqrtf(var[k] + 1e-3f);
      W2frag[idx] = f32_to_bf16_rne(s * W[(size_t)k * DF + c]);
    }
  } else {
    if (t < DF) {
      int c = t;
      float acc = b[c];
      for (int k = 0; k < DF; ++k) {
        float s = gamma[k] * rsqrtf(var[k] + 1e-3f);
        float tt = beta[k] - mean[k] * s;
        acc += tt * W[(size_t)k * DF + c];
      }
      bias2[c] = acc;
    }
  }
}

// ---------------- scans (in-place over gbase) ----------------
__global__ __launch_bounds__(256) void scan1_kernel(
    int* __restrict__ data, int* __restrict__ bsum, int n) {
  __shared__ int s[256];
  int t = threadIdx.x;
  int base = blockIdx.x * SCAN_ELEMS + t * 8;
  int v[8];
  int tsum = 0;
#pragma unroll
  for (int k = 0; k < 8; ++k) {
    v[k] = (base + k < n) ? data[base + k] : 0;
    tsum += v[k];
  }
  s[t] = tsum;
  __syncthreads();
  for (int off = 1; off < 256; off <<= 1) {
    int tmp = (t >= off) ? s[t - off] : 0;
    __syncthreads();
    s[t] += tmp;
    __syncthreads();
  }
  int run = s[t] - tsum;
#pragma unroll
  for (int k = 0; k < 8; ++k) {
    if (base + k < n) data[base + k] = run;
    run += v[k];
  }
  if (t == 255) bsum[blockIdx.x] = s[255];
}

__global__ __launch_bounds__(256) void scan23_kernel(
    int* __restrict__ data, const int* __restrict__ bsum, int n, int nbA,
    int* __restrict__ ctr) {
  __shared__ int s[256];
  int t = threadIdx.x;
  int v = (t < nbA) ? bsum[t] : 0;
  s[t] = v;
  __syncthreads();
  for (int off = 1; off < 256; off <<= 1) {
    int tmp = (t >= off) ? s[t - off] : 0;
    __syncthreads();
    s[t] += tmp;
    __syncthreads();
  }
  int i = blockIdx.x * 256 + t;
  if (i < n) {
    int blk = i >> 11;  // SCAN_ELEMS = 2048
    int add = (blk == 0) ? 0 : s[blk - 1];
    data[i] += add;
  }
  if (blockIdx.x == 0 && t == 0) {
    data[n] = s[nbA - 1];
    ctr[0] = 0;  // work-stealing queue init (replaces memset launch)
  }
}

// ---------------- scatter into bucket-sorted payload ----------------
__global__ __launch_bounds__(512) void scatter_blk_kernel(
    const int* __restrict__ esrc, const int* __restrict__ edst,
    const float* __restrict__ ew, const int* __restrict__ gbase,
    uint2* __restrict__ payload, int E, int nbk, int chunk) {
  extern __shared__ int cur[];
  int bblk = blockIdx.x;
  int t = threadIdx.x;
  for (int k = t; k < nbk; k += 512) cur[k] = gbase[(size_t)k * NB + bblk];
  __syncthreads();
  int e0 = bblk * chunk;
  int e1 = min(E, e0 + chunk);
  for (int e = e0 + t; e < e1; e += 512) {
    int d = edst[e];
    int k = d >> BKSH;
    int pos = atomicAdd(&cur[k], 1);
    uint2 v;
    v.x = (unsigned)esrc[e] | ((unsigned)(d & (BKNODES - 1)) << 17);
    v.y = __float_as_uint(ew[e]);
    payload[pos] = v;
  }
}

// ---------------- persistent fused reorder + pull (round-12 verified) ------
__global__ __launch_bounds__(1024, 8) void reorder_pull_kernel(
    const unsigned* __restrict__ Hb, const uint2* __restrict__ payload,
    const int* __restrict__ gbase, unsigned* __restrict__ hb_out,
    int* __restrict__ ctr, int N, int nbk) {
  __shared__ uint2 stage[CAP2];    // 24 KB
  __shared__ uint2 sorted[CAP2];   // 24 KB
  __shared__ int cnt[BKNODES];
  __shared__ int scn[BKNODES];
  __shared__ int cur[BKNODES];
  __shared__ int s_bk;
  int t = threadIdx.x;
  int wid = t >> 6;
  int lane = t & 63;

  for (;;) {
    if (t == 0) s_bk = atomicAdd(ctr, 1);
    __syncthreads();
    int bk = s_bk;
    if (bk >= nbk) return;
    int base = gbase[(size_t)bk * NB];
    int end  = gbase[(size_t)(bk + 1) * NB];
    int len = end - base;

    if (len <= CAP2) {
      if (t < BKNODES) cnt[t] = 0;
      __syncthreads();
      // single global read of the segment: stage + count
      for (int j = t; j < len; j += 1024) {
        uint2 m = payload[base + j];
        stage[j] = m;
        atomicAdd(&cnt[m.x >> 17], 1);
      }
      __syncthreads();
      if (t < BKNODES) scn[t] = cnt[t];
      __syncthreads();
      for (int off = 1; off < BKNODES; off <<= 1) {
        int tmp = (t < BKNODES && t >= off) ? scn[t - off] : 0;
        __syncthreads();
        if (t < BKNODES) scn[t] += tmp;
        __syncthreads();
      }
      if (t < BKNODES) cur[t] = scn[t] - cnt[t];
      __syncthreads();
      // LDS -> LDS bucket sort
      for (int j = t; j < len; j += 1024) {
        uint2 m = stage[j];
        int pos = atomicAdd(&cur[m.x >> 17], 1);
        uint2 o;
        o.x = m.x & 0x1FFFFu;
        o.y = m.y;
        sorted[pos] = o;
      }
      __syncthreads();

      // gather: wave handles 4 nodes; 8 independent row gathers in flight
#pragma unroll
      for (int i = 0; i < 4; ++i) {
        int dl = wid * 4 + i;
        int node = (bk << BKSH) + dl;
        if (node >= N) break;
        int s1 = scn[dl];
        int s0 = s1 - cnt[dl];
        float ax = 0.0f, ay = 0.0f;
        int j = s0;
        for (; j + 8 <= s1; j += 8) {
          uint2 m[8];
#pragma unroll
          for (int k = 0; k < 8; ++k) m[k] = sorted[j + k];  // LDS broadcast
          float lo[8], hi[8];
#pragma unroll
          for (int k = 0; k < 8; ++k) {
            unsigned p = Hb[(size_t)m[k].x * 64 + lane];
            lo[k] = __uint_as_float(p << 16);
            hi[k] = __uint_as_float(p & 0xFFFF0000u);
          }
#pragma unroll
          for (int k = 0; k < 8; ++k) {
            float w = __uint_as_float(m[k].y);
            ax = fmaf(lo[k], w, ax);
            ay = fmaf(hi[k], w, ay);
          }
        }
        for (; j < s1; ++j) {
          uint2 m = sorted[j];
          float w = __uint_as_float(m.y);
          unsigned p = Hb[(size_t)m.x * 64 + lane];
          ax = fmaf(__uint_as_float(p << 16), w, ax);
          ay = fmaf(__uint_as_float(p & 0xFFFF0000u), w, ay);
        }
        unsigned pack = (unsigned)f32_to_bf16_rne(ax) |
                        ((unsigned)f32_to_bf16_rne(ay) << 16);
        hb_out[(size_t)node * 64 + lane] = pack;
      }
    } else {
      // Pathological bucket (>CAP2): filter-scan, correct but slow.
      for (int i = 0; i < 4; ++i) {
        int dl = wid * 4 + i;
        int node = (bk << BKSH) + dl;
        if (node >= N) break;
        float ax = 0.0f, ay = 0.0f;
        for (int j = base; j < end; ++j) {
          uint2 m = payload[j];
          if ((int)(m.x >> 17) == dl) {
            float w = __uint_as_float(m.y);
            unsigned p = Hb[(size_t)(m.x & 0x1FFFFu) * 64 + lane];
            ax = fmaf(__uint_as_float(p << 16), w, ax);
            ay = fmaf(__uint_as_float(p & 0xFFFF0000u), w, ay);
          }
        }
        unsigned pack = (unsigned)f32_to_bf16_rne(ax) |
                        ((unsigned)f32_to_bf16_rne(ay) << 16);
        hb_out[(size_t)node * 64 + lane] = pack;
      }
    }
    __syncthreads();  // LDS reuse + s_bk rewrite safety
  }
}

// ---------------- MFMA GEMM + GELU (BN pre-folded), 2 row-groups/block -----
__global__ __launch_bounds__(256) void mfma_gemm_gelu_kernel(
    const unsigned short* __restrict__ hb,      // [N][128] bf16
    const unsigned short* __restrict__ W2frag,  // fragment-ordered bf16
    const float* __restrict__ bias2,            // [128]
    float* __restrict__ out, int N, int ngrp) {
  __shared__ unsigned short sW[8 * 4 * 64 * 8];  // 32 KB

  int t = threadIdx.x;
  {
    const uint4* src = (const uint4*)W2frag;
    uint4* dst = (uint4*)sW;
    for (int i = t; i < 2048; i += 256) dst[i] = src[i];
  }
  __syncthreads();

  int wid = t >> 6;
  int l = t & 63;
  const short8* wf = (const short8*)sW;
  int orow = (l >> 4) * 4;  // C/D: row=(lane>>4)*4+reg, col=lane&15 (m89)
  int ocol = l & 15;

#pragma unroll
  for (int g = 0; g < 2; ++g) {
    int grp = blockIdx.x * 2 + g;
    if (grp >= ngrp) break;
    int row0 = grp * 64 + wid * 16;

    int arow = row0 + (l & 15);
    if (arow >= N) arow = N - 1;  // clamp (stores guarded)
    const short8* hrow = (const short8*)(hb + (size_t)arow * DF);
    int asub = l >> 4;
    short8 a[4];
#pragma unroll
    for (int kt = 0; kt < 4; ++kt) a[kt] = hrow[kt * 4 + asub];

#pragma unroll
    for (int ct = 0; ct < 8; ++ct) {
      f32x4 acc = {0.0f, 0.0f, 0.0f, 0.0f};
#pragma unroll
      for (int kt = 0; kt < 4; ++kt) {
        short8 bfr = wf[(ct * 4 + kt) * 64 + l];
        acc = __builtin_amdgcn_mfma_f32_16x16x32_bf16(a[kt], bfr, acc, 0, 0, 0);
      }
      int col = ct * 16 + ocol;
      float bb = bias2[col];
#pragma unroll
      for (int r = 0; r < 4; ++r) {
        int row = row0 + orow + r;
        if (row < N) {
          float x = acc[r] + bb;
          float gv = 0.5f * x * (1.0f + erff(x * 0.70710678118654752440f));
          out[(size_t)row * DF + col] = gv;
        }
      }
    }
  }
}

// ---------------- tier-B kernels (round-8 verified) ----------------
__global__ __launch_bounds__(256) void reorder2_kernel(
    const uint2* __restrict__ payload, const int* __restrict__ gbase,
    uint2* __restrict__ csr, int* __restrict__ rowptr,
    int N, int nbk, int E) {
  __shared__ uint2 stage[CAP];
  __shared__ int cnt[BKNODES];
  __shared__ int s64[BKNODES];
  __shared__ int cur[BKNODES];
  int bk = blockIdx.x;
  int t = threadIdx.x;
  int base = gbase[(size_t)bk * NB];
  int end  = gbase[(size_t)(bk + 1) * NB];
  int len = end - base;
  bool fit = (len <= CAP);

  if (t < BKNODES) cnt[t] = 0;
  __syncthreads();
  if (fit) {
    for (int j = t; j < len; j += 256) {
      uint2 m = payload[base + j];
      stage[j] = m;
      atomicAdd(&cnt[m.x >> 17], 1);
    }
  } else {
    for (int j = t; j < len; j += 256)
      atomicAdd(&cnt[payload[base + j].x >> 17], 1);
  }
  __syncthreads();
  if (t < BKNODES) s64[t] = cnt[t];
  __syncthreads();
  for (int off = 1; off < BKNODES; off <<= 1) {
    int tmp = 0;
    if (t < BKNODES && t >= off) tmp = s64[t - off];
    __syncthreads();
    if (t < BKNODES) s64[t] += tmp;
    __syncthreads();
  }
  if (t < BKNODES) {
    int ex = s64[t] - cnt[t];
    cur[t] = ex;
    int node = (bk << BKSH) + t;
    if (node < N) rowptr[node] = base + ex;
  }
  if (bk == nbk - 1 && t == 0) rowptr[N] = E;
  __syncthreads();
  if (fit) {
    for (int j = t; j < len; j += 256) {
      uint2 m = stage[j];
      int dl = (int)(m.x >> 17);
      int pos = atomicAdd(&cur[dl], 1);
      uint2 o;
      o.x = m.x & 0x1FFFFu;
      o.y = m.y;
      csr[(size_t)base + pos] = o;
    }
  } else {
    for (int j = t; j < len; j += 256) {
      uint2 m = payload[base + j];
      int dl = (int)(m.x >> 17);
      int pos = atomicAdd(&cur[dl], 1);
      uint2 o;
      o.x = m.x & 0x1FFFFu;
      o.y = m.y;
      csr[(size_t)base + pos] = o;
    }
  }
}

__global__ __launch_bounds__(256) void pull_csr_f32_kernel(
    const float2* __restrict__ H2, const int* __restrict__ rowptr,
    const uint2* __restrict__ csr_sw, float* __restrict__ h, int N) {
  int wave = threadIdx.x >> 6;
  int lane = threadIdx.x & 63;
  int node = blockIdx.x * 4 + wave;
  if (node >= N) return;
  int rs = rowptr[node];
  int re = rowptr[node + 1];
  float ax = 0.0f, ay = 0.0f;
  for (int j = rs; j < re; ++j) {
    uint2 m = csr_sw[j];
    float w = __uint_as_float(m.y);
    float2 u = H2[(size_t)m.x * 64 + lane];
    ax = fmaf(u.x, w, ax);
    ay = fmaf(u.y, w, ay);
  }
  float2 r;
  r.x = ax;
  r.y = ay;
  reinterpret_cast<float2*>(h)[(size_t)node * 64 + lane] = r;
}

__global__ __launch_bounds__(256) void fused_bn_gemm_gelu(
    float* __restrict__ hout, const float* __restrict__ gamma,
    const float* __restrict__ beta, const float* __restrict__ mean,
    const float* __restrict__ var, const float* __restrict__ W,
    const float* __restrict__ b, int N) {
  __shared__ float s_s[DF];
  __shared__ float s_t[DF];
  __shared__ float s_hb[16][DF];
  __shared__ float s_W[32][DF];

  int t = threadIdx.x;
  if (t < DF) {
    float sv = gamma[t] * rsqrtf(var[t] + 1e-3f);
    s_s[t] = sv;
    s_t[t] = beta[t] - mean[t] * sv;
  }
  __syncthreads();

  int n0 = blockIdx.x * 16;
  for (int i = t; i < 16 * DF; i += 256) {
    int r = i >> 7;
    int c = i & (DF - 1);
    int node = n0 + r;
    float hv = (node < N) ? hout[(size_t)node * DF + c] : 0.0f;
    s_hb[r][c] = hv * s_s[c] + s_t[c];
  }

  float acc[8];
#pragma unroll
  for (int i = 0; i < 8; i++) acc[i] = 0.0f;

  int col = t & (DF - 1);
  int half = t >> 7;

  for (int kc = 0; kc < DF; kc += 32) {
    __syncthreads();
    for (int i = t; i < 32 * DF; i += 256) {
      int r = i >> 7;
      int c = i & (DF - 1);
      s_W[r][c] = W[(size_t)(kc + r) * DF + c];
    }
    __syncthreads();
#pragma unroll
    for (int kk = 0; kk < 32; kk++) {
      float wv = s_W[kk][col];
#pragma unroll
      for (int i = 0; i < 8; i++) {
        acc[i] += s_hb[half + i * 2][kc + kk] * wv;
      }
    }
  }

  float bb = b[col];
#pragma unroll
  for (int i = 0; i < 8; i++) {
    int node = n0 + half + i * 2;
    if (node < N) {
      float x = acc[i] + bb;
      float g = 0.5f * x * (1.0f + erff(x * 0.70710678118654752440f));
      hout[(size_t)node * DF + col] = g;
    }
  }
}

extern "C" void kernel_launch(void* const* d_in, const int* in_sizes, int n_in,
                              void* d_out, int out_size, void* d_ws, size_t ws_size,
                              hipStream_t stream) {
  const float* H     = (const float*)d_in[0];
  const int*   esrc  = (const int*)d_in[1];
  const int*   edst  = (const int*)d_in[2];
  const float* ew    = (const float*)d_in[3];
  const float* gamma = (const float*)d_in[4];
  const float* beta  = (const float*)d_in[5];
  const float* mean  = (const float*)d_in[6];
  const float* var   = (const float*)d_in[7];
  const float* W     = (const float*)d_in[8];
  const float* b     = (const float*)d_in[9];

  int N = in_sizes[0] / DF;
  int E = in_sizes[1];
  float* h = (float*)d_out;

  int nbk = (N + BKNODES - 1) / BKNODES;          // 1563
  int NBKG = nbk * NB;                             // 400128
  int nbA = (NBKG + SCAN_ELEMS - 1) / SCAN_ELEMS;  // 196 <= 256
  int chunk = (E + NB - 1) / NB;                   // 12500

  size_t off = 0;
  auto alloc = [&](size_t bytes) {
    size_t o = off;
    off += (bytes + 255) & ~(size_t)255;
    return o;
  };
  size_t o_gbase  = alloc((size_t)(NBKG + 1) * 4);  // counts -> scanned bases
  size_t o_bsum   = alloc((size_t)(nbA + 1) * 4);
  size_t o_rowptr = alloc((size_t)(N + 1) * 4);     // tier B only
  size_t o_w2     = alloc((size_t)16384 * 2);
  size_t o_bias2  = alloc((size_t)DF * 4);
  size_t o_ctr    = alloc(256);
  size_t o_pl     = alloc((size_t)E * 8);
  size_t o_csr    = alloc((size_t)E * 8);   // tier A: reused as bf16 h out
  size_t need_bin = off;
  size_t o_hb     = alloc((size_t)N * DF * 2);
  size_t need_bf16 = off;

  char* ws = (char*)d_ws;

  if (ws_size >= need_bin) {
    int* gbase   = (int*)(ws + o_gbase);
    int* bsum    = (int*)(ws + o_bsum);
    int* rowptr  = (int*)(ws + o_rowptr);
    unsigned short* W2frag = (unsigned short*)(ws + o_w2);
    float* bias2 = (float*)(ws + o_bias2);
    int* ctr     = (int*)(ws + o_ctr);
    uint2* payload = (uint2*)(ws + o_pl);
    uint2* csr     = (uint2*)(ws + o_csr);
    bool tierA = (ws_size >= need_bf16 && (size_t)N * DF * 2 <= (size_t)E * 8);

    size_t lds_bytes = (size_t)nbk * 4;

    if (tierA) {
      ushort4* Hb = (ushort4*)(ws + o_hb);
      int n4 = N * DF / 4;                        // 3.2M
      int h_blocks = (n4 + 511) / 512;            // 6250
      int grid = NB + h_blocks + 32 + 1;
      hist_prep_kernel<<<grid, 512, lds_bytes, stream>>>(
          edst, gbase, E, nbk, chunk,
          (const float4*)H, Hb, n4,
          W, gamma, beta, mean, var, b, W2frag, bias2, NB, h_blocks);
      scan1_kernel<<<nbA, 256, 0, stream>>>(gbase, bsum, NBKG);
      scan23_kernel<<<(NBKG + 255) / 256, 256, 0, stream>>>(gbase, bsum, NBKG,
                                                            nbA, ctr);
      scatter_blk_kernel<<<NB, 512, lds_bytes, stream>>>(esrc, edst, ew, gbase,
                                                         payload, E, nbk, chunk);
      unsigned* hb_out = (unsigned*)(ws + o_csr);  // csr space reused
      int pgrid = min(PBLOCKS, nbk);
      reorder_pull_kernel<<<pgrid, 1024, 0, stream>>>(
          (const unsigned*)Hb, payload, gbase, hb_out, ctr, N, nbk);
      int ngrp = (N + 63) / 64;
      mfma_gemm_gelu_kernel<<<(ngrp + 1) / 2, 256, 0, stream>>>(
          (const unsigned short*)hb_out, W2frag, bias2, (float*)d_out, N, ngrp);
    } else {
      hist_prep_kernel<<<NB, 512, lds_bytes, stream>>>(
          edst, gbase, E, nbk, chunk,
          (const float4*)H, (ushort4*)(ws + o_pl) /*unused*/, 0,
          W, gamma, beta, mean, var, b, W2frag, bias2, NB, 0);
      scan1_kernel<<<nbA, 256, 0, stream>>>(gbase, bsum, NBKG);
      scan23_kernel<<<(NBKG + 255) / 256, 256, 0, stream>>>(gbase, bsum, NBKG,
                                                            nbA, ctr);
      scatter_blk_kernel<<<NB, 512, lds_bytes, stream>>>(esrc, edst, ew, gbase,
                                                         payload, E, nbk, chunk);
      reorder2_kernel<<<nbk, 256, 0, stream>>>(payload, gbase, csr, rowptr,
                                               N, nbk, E);
      pull_csr_f32_kernel<<<(N + 3) / 4, 256, 0, stream>>>(
          (const float2*)H, rowptr, csr, h, N);
      fused_bn_gemm_gelu<<<(N + 15) / 16, 256, 0, stream>>>(h, gamma, beta,
                                                            mean, var, W, b, N);
    }
  } else {
    hipMemsetAsync(d_out, 0, (size_t)out_size * sizeof(float), stream);
    long long threads = (long long)E * 32;
    long long grid = (threads + 255) / 256;
    scatter_kernel<<<(int)grid, 256, 0, stream>>>(H, esrc, edst, ew, h, E);
    fused_bn_gemm_gelu<<<(N + 15) / 16, 256, 0, stream>>>(h, gamma, beta,
                                                          mean, var, W, b, N);
  }
}